// Round 13
// baseline (427.926 us; speedup 1.0000x reference)
//
#include <hip/hip_runtime.h>
#include <hip/hip_bf16.h>
#include <type_traits>

#define BQ   256
#define NTR  50000
#define DD   3072
#define NSP  50048          // padded N stride (multiple of 64)
#define NBLK 782
#define CAP  4096
#define DELTA 18.0f

typedef __fp16 f16;
typedef __fp16 f16x2 __attribute__((ext_vector_type(2)));
typedef __fp16 f16x8 __attribute__((ext_vector_type(8)));
typedef float  f32x4 __attribute__((ext_vector_type(4)));

__device__ __forceinline__ void gload_lds16(const void* g, void* l) {
    __builtin_amdgcn_global_load_lds(
        (const __attribute__((address_space(1))) unsigned int*)g,
        (__attribute__((address_space(3))) unsigned int*)l, 16, 0, 0);
}

// ---------------- P0: convert x (f32) -> fp16, fragment-major pack ----------------
__global__ __launch_bounds__(256) void kx(const float* __restrict__ x, f16* __restrict__ xp) {
    const int t = blockIdx.x * 256 + threadIdx.x;   // t = g*256 + r, grid = 384*256
    const int g = t >> 8, r = t & 255;
    const f32x4* src = (const f32x4*)(x + (size_t)r * DD + (g << 3));
    f32x4 a = src[0], b = src[1];
    union { f16x2 h2[4]; f16x8 h8; } u;
    u.h2[0] = __builtin_amdgcn_cvt_pkrtz(a[0], a[1]);
    u.h2[1] = __builtin_amdgcn_cvt_pkrtz(a[2], a[3]);
    u.h2[2] = __builtin_amdgcn_cvt_pkrtz(b[0], b[1]);
    u.h2[3] = __builtin_amdgcn_cvt_pkrtz(b[2], b[3]);
    ((f16x8*)xp)[t] = u.h8;
}

// ---------------- P1: S = X*Y^T - 0.5*|y|^2 — T3/T4 deep-pipeline ----------------
// y: global_load_lds f32 into 4-deep LDS ring (3 batches always in flight, 48KB);
// A: global_load_lds from L2 into 2-deep LDS (32KB in flight). Counted
// s_waitcnt vmcnt(6) + raw barriers — vmcnt NEVER drains to 0 in the main loop.
// Both-sides XOR swizzle: pre-swizzled global src, linear DMA dest, swizzled read.
__global__ __launch_bounds__(512, 2) void kqk(
    const f16* __restrict__ xp, const float* __restrict__ y,
    float* __restrict__ S, float* __restrict__ pmax) {
    __shared__ char Ys[4][16384];   // 64 rows x 256 B f32 per buf
    __shared__ char As[2][32768];   // 8 chunks x 256 rows x 16 B fp16 per buf

    const int tid = threadIdx.x;
    const int blk = blockIdx.x;
    const int n0  = blk * 64;
    const int w = tid >> 6, l = tid & 63;
    const int l15 = l & 15, lg = l >> 4;

    // --- staging sources (pre-swizzled per-lane global addresses) ---
    // y: unit D = (w*2+i)*64 + l covers (row = D>>4, u = D&15); src k-unit = u ^ (row&7)
    const char* ysrc[2];
    #pragma unroll
    for (int i = 0; i < 2; ++i) {
        int D = (((w << 1) + i) << 6) + l;
        int row = D >> 4, u = D & 15;
        int grow = n0 + row; grow = grow < NTR ? grow : NTR - 1;
        ysrc[i] = (const char*)y + (size_t)grow * (DD * 4) + ((u ^ (row & 7)) << 4);
    }
    // A: unit U = (w*4+i)*64 + l covers (chunk = U>>8, row = U&255), linear
    const char* asrc[4];
    #pragma unroll
    for (int i = 0; i < 4; ++i) {
        int U = (((w << 2) + i) << 6) + l;
        asrc[i] = (const char*)xp + ((size_t)U << 4);
    }

    auto stageY = [&](int buf, int ks) {
        #pragma unroll
        for (int i = 0; i < 2; ++i)
            gload_lds16(ysrc[i] + (ks << 8), &Ys[buf][(((w << 1) + i) << 10)]);
    };
    auto stageA = [&](int buf, int ks) {
        #pragma unroll
        for (int i = 0; i < 4; ++i)
            gload_lds16(asrc[i] + ((size_t)ks << 15), &As[buf][(((w << 2) + i) << 10)]);
    };

    // prologue: y(0..2), A(0) in flight
    stageY(0, 0); stageY(1, 1); stageY(2, 2); stageA(0, 0);

    f32x4 acc[2][4] = {};
    float y2a[4] = {0.f, 0.f, 0.f, 0.f};

    for (int ks = 0; ks < 48; ++ks) {
        if (ks + 3 < 48) stageY((ks + 3) & 3, ks + 3);
        if (ks + 1 < 48) stageA((ks + 1) & 1, ks + 1);
        // counted wait: exactly the 6 loads issued after A(ks) remain; never 0 mid-loop
        if (ks <= 44)      asm volatile("s_waitcnt vmcnt(6)" ::: "memory");
        else if (ks < 47)  asm volatile("s_waitcnt vmcnt(4)" ::: "memory");
        else               asm volatile("s_waitcnt vmcnt(0)" ::: "memory");
        __builtin_amdgcn_s_barrier();

        const char* Yc = Ys[ks & 3];
        const char* Ac = As[ks & 1];
        #pragma unroll
        for (int kk = 0; kk < 2; ++kk) {
            f16x8 af[2];
            #pragma unroll
            for (int fm = 0; fm < 2; ++fm)
                af[fm] = *(const f16x8*)(Ac + (((((kk << 2) + lg) << 8) + (w << 5) + (fm << 4) + l15) << 4));
            f16x8 bf[4];
            #pragma unroll
            for (int fn = 0; fn < 4; ++fn) {
                const int row = (fn << 4) + l15;
                const int v0 = (kk << 3) + (lg << 1);
                f32x4 lo = *(const f32x4*)(Yc + (((row << 4) + (v0 ^ (row & 7))) << 4));
                f32x4 hi = *(const f32x4*)(Yc + (((row << 4) + ((v0 + 1) ^ (row & 7))) << 4));
                if (w == 0) {
                    y2a[fn] += lo[0]*lo[0] + lo[1]*lo[1] + lo[2]*lo[2] + lo[3]*lo[3]
                             + hi[0]*hi[0] + hi[1]*hi[1] + hi[2]*hi[2] + hi[3]*hi[3];
                }
                union { f16x2 h2[4]; f16x8 h8; } u;
                u.h2[0] = __builtin_amdgcn_cvt_pkrtz(lo[0], lo[1]);
                u.h2[1] = __builtin_amdgcn_cvt_pkrtz(lo[2], lo[3]);
                u.h2[2] = __builtin_amdgcn_cvt_pkrtz(hi[0], hi[1]);
                u.h2[3] = __builtin_amdgcn_cvt_pkrtz(hi[2], hi[3]);
                bf[fn] = u.h8;
            }
            #pragma unroll
            for (int fm = 0; fm < 2; ++fm)
                #pragma unroll
                for (int fn = 0; fn < 4; ++fn)
                    acc[fm][fn] = __builtin_amdgcn_mfma_f32_16x16x32_f16(af[fm], bf[fn], acc[fm][fn], 0, 0, 0);
        }
        __builtin_amdgcn_s_barrier();   // reads done -> next iter may overwrite bufs
    }

    // epilogue: y2 (wave 0 holds full sums over all kk) -> LDS broadcast
    float* lys = (float*)&Ys[0][0];
    #pragma unroll
    for (int fn = 0; fn < 4; ++fn) {
        float v = y2a[fn];
        v += __shfl_xor(v, 16, 64);
        v += __shfl_xor(v, 32, 64);
        y2a[fn] = v;
    }
    if (w == 0 && lg == 0) {
        #pragma unroll
        for (int fn = 0; fn < 4; ++fn) lys[(fn << 4) + l15] = y2a[fn];
    }
    __syncthreads();
    float ly2[4];
    #pragma unroll
    for (int fn = 0; fn < 4; ++fn) ly2[fn] = 0.5f * lys[(fn << 4) + l15];
    // per-row max over this block's 64 cols (pad cols masked)
    #pragma unroll
    for (int fm = 0; fm < 2; ++fm) {
        #pragma unroll
        for (int j = 0; j < 4; ++j) {
            float rm = -3.4e38f;
            #pragma unroll
            for (int fn = 0; fn < 4; ++fn) {
                int col = n0 + (fn << 4) + l15;
                float sc = acc[fm][fn][j] - ly2[fn];
                rm = (col < NTR) ? fmaxf(rm, sc) : rm;
            }
            #pragma unroll
            for (int off = 1; off < 16; off <<= 1) rm = fmaxf(rm, __shfl_xor(rm, off, 64));
            if (l15 == 0)
                pmax[(size_t)((w << 5) + (fm << 4) + (lg << 2) + j) * NBLK + blk] = rm;
        }
    }
    // S = x.y - 0.5|y|^2
    #pragma unroll
    for (int fm = 0; fm < 2; ++fm) {
        int row0 = (w << 5) + (fm << 4) + (lg << 2);
        #pragma unroll
        for (int fn = 0; fn < 4; ++fn) {
            int col = n0 + (fn << 4) + l15;
            float* sp = S + (size_t)row0 * NSP + col;
            sp[0]               = acc[fm][fn][0] - ly2[fn];
            sp[NSP]             = acc[fm][fn][1] - ly2[fn];
            sp[2 * (size_t)NSP] = acc[fm][fn][2] - ly2[fn];
            sp[3 * (size_t)NSP] = acc[fm][fn][3] - ly2[fn];
        }
    }
}

// ---------------- P2: row max from pmax + candidate selection ----------------
__global__ __launch_bounds__(256) void ksel(
    const float* __restrict__ S, const float* __restrict__ pmax,
    const float* __restrict__ sig, unsigned* __restrict__ cnt,
    unsigned* __restrict__ cand) {
    __shared__ float red[4];
    const int b = blockIdx.x, tid = threadIdx.x;
    const float s2 = sig[b] * sig[b];
    const float* pm = pmax + (size_t)b * NBLK;
    float mx = -3.4e38f;
    for (int i = tid; i < NBLK; i += 256) mx = fmaxf(mx, pm[i]);
    #pragma unroll
    for (int o = 1; o < 64; o <<= 1) mx = fmaxf(mx, __shfl_xor(mx, o, 64));
    if ((tid & 63) == 0) red[tid >> 6] = mx;
    __syncthreads();
    mx = fmaxf(fmaxf(red[0], red[1]), fmaxf(red[2], red[3]));
    const float thr = mx - DELTA * s2;
    const f32x4* rowv = (const f32x4*)(S + (size_t)b * NSP);
    for (int i = tid; i < 12500; i += 256) {
        f32x4 s = rowv[i];
        #pragma unroll
        for (int j = 0; j < 4; ++j) {
            if (s[j] >= thr) {
                unsigned idx = atomicAdd(&cnt[b], 1u);
                if (idx < CAP) cand[(size_t)b * CAP + idx] = (unsigned)(4 * i + j);
            }
        }
    }
}

// ---------------- P3: fused exact rescoring + online softmax + PV ----------------
__global__ __launch_bounds__(512) void kpv(
    const float* __restrict__ x, const float* __restrict__ y,
    const float* __restrict__ sig, const unsigned* __restrict__ cnt,
    const unsigned* __restrict__ cand, float* __restrict__ out) {
    __shared__ float xs[DD];
    __shared__ unsigned ci[CAP];
    __shared__ float om[8], ol[8];
    __shared__ float sumv[DD];
    const int b = blockIdx.x, tid = threadIdx.x;
    const int c = (int)(cnt[b] < (unsigned)CAP ? cnt[b] : (unsigned)CAP);
    const float s2 = sig[b] * sig[b];
    const float isc = -0.5f / s2;
    for (int i = tid; i < DD; i += 512) xs[i] = x[(size_t)b * DD + i];
    for (int i = tid; i < c; i += 512) ci[i] = cand[(size_t)b * CAP + i];
    __syncthreads();
    const int w = tid >> 6, l = tid & 63;
    const f32x4* xr = (const f32x4*)xs;

    f32x4 o[12] = {};
    float m = -3.4e38f, ll = 0.f;
    f32x4 A[12], Bv[12];

    auto LD = [&](f32x4* dst, int i) {
        const f32x4* yr = (const f32x4*)(y + (size_t)ci[i] * DD);
        #pragma unroll
        for (int j = 0; j < 12; ++j) dst[j] = yr[(j << 6) + l];
    };
    auto PROC = [&](f32x4* src) {
        float d2 = 0.f;
        #pragma unroll
        for (int j = 0; j < 12; ++j) {
            f32x4 xv = xr[(j << 6) + l];
            float a0 = xv[0]-src[j][0], a1 = xv[1]-src[j][1],
                  a2 = xv[2]-src[j][2], a3 = xv[3]-src[j][3];
            d2 += a0*a0 + a1*a1 + a2*a2 + a3*a3;
        }
        #pragma unroll
        for (int off = 1; off < 64; off <<= 1) d2 += __shfl_xor(d2, off, 64);
        float s = d2 * isc;
        float mn = fmaxf(m, s);
        float f = __expf(m - mn);
        float wi = __expf(s - mn);
        #pragma unroll
        for (int j = 0; j < 12; ++j) o[j] = o[j] * f + wi * src[j];
        ll = ll * f + wi;
        m = mn;
    };

    int i = w;
    if (i < c) LD(A, i);
    for (; i < c; i += 16) {
        int i2 = i + 8;
        if (i2 < c) LD(Bv, i2);
        PROC(A);
        if (i2 < c) {
            if (i + 16 < c) LD(A, i + 16);
            PROC(Bv);
        }
    }
    om[w] = m; ol[w] = ll;
    __syncthreads();
    float M = om[0];
    #pragma unroll
    for (int ww = 1; ww < 8; ++ww) M = fmaxf(M, om[ww]);
    float Ls = 0.f;
    #pragma unroll
    for (int ww = 0; ww < 8; ++ww) Ls += ol[ww] * __expf(om[ww] - M);
    const float fw = __expf(m - M);
    f32x4* sv = (f32x4*)sumv;
    if (w == 0) {
        #pragma unroll
        for (int j = 0; j < 12; ++j) sv[(j << 6) + l] = o[j] * fw;
    }
    __syncthreads();
    for (int ww = 1; ww < 8; ++ww) {
        if (w == ww) {
            #pragma unroll
            for (int j = 0; j < 12; ++j) sv[(j << 6) + l] += o[j] * fw;
        }
        __syncthreads();
    }
    const float inv = 1.f / Ls;
    f32x4* od = (f32x4*)(out + (size_t)b * DD);
    for (int t = tid; t < 768; t += 512) od[t] = sv[t] * inv;
}

extern "C" void kernel_launch(void* const* d_in, const int* in_sizes, int n_in,
                              void* d_out, int out_size, void* d_ws, size_t ws_size,
                              hipStream_t stream) {
    const float* x   = (const float*)d_in[0];
    const float* sig = (const float*)d_in[1];
    const float* y   = (const float*)d_in[2];
    float* out = (float*)d_out;
    char* ws = (char*)d_ws;
    f16*      xp   = (f16*)(ws);                  // 1,572,864
    unsigned* cnt  = (unsigned*)(ws + 1572864);   // 1,024
    unsigned* cand = (unsigned*)(ws + 1573888);   // 4,194,304
    float*    pmax = (float*)(ws + 5768192);      // 256*782*4 = 800,768
    float*    S    = (float*)(ws + 6568960);      // 256*50048*4 = 51,249,152

    (void)hipMemsetAsync(cnt, 0, 256 * sizeof(unsigned), stream);
    kx  <<<384, 256, 0, stream>>>(x, xp);
    kqk <<<NBLK, 512, 0, stream>>>(xp, y, S, pmax);
    ksel<<<256, 256, 0, stream>>>(S, pmax, sig, cnt, cand);
    kpv <<<256, 512, 0, stream>>>(x, y, sig, cnt, cand, out);
}

// Round 14
// 361.537 us; speedup vs baseline: 1.1836x; 1.1836x over previous
//
#include <hip/hip_runtime.h>
#include <hip/hip_bf16.h>
#include <type_traits>

#define BQ   256
#define NTR  50000
#define DD   3072
#define NSP  50048          // padded N stride (multiple of 64)
#define NBLK 782
#define CAP  4096
#define DELTA 18.0f

typedef __fp16 f16;
typedef __fp16 f16x2 __attribute__((ext_vector_type(2)));
typedef __fp16 f16x8 __attribute__((ext_vector_type(8)));
typedef float  f32x4 __attribute__((ext_vector_type(4)));

__device__ __forceinline__ void gload_lds16(const void* g, void* l) {
    __builtin_amdgcn_global_load_lds(
        (const __attribute__((address_space(1))) unsigned int*)g,
        (__attribute__((address_space(3))) unsigned int*)l, 16, 0, 0);
}

// ---------------- P0: convert x (f32) -> fp16, fragment-major pack ----------------
__global__ __launch_bounds__(256) void kx(const float* __restrict__ x, f16* __restrict__ xp) {
    const int t = blockIdx.x * 256 + threadIdx.x;   // t = g*256 + r, grid = 384*256
    const int g = t >> 8, r = t & 255;
    const f32x4* src = (const f32x4*)(x + (size_t)r * DD + (g << 3));
    f32x4 a = src[0], b = src[1];
    union { f16x2 h2[4]; f16x8 h8; } u;
    u.h2[0] = __builtin_amdgcn_cvt_pkrtz(a[0], a[1]);
    u.h2[1] = __builtin_amdgcn_cvt_pkrtz(a[2], a[3]);
    u.h2[2] = __builtin_amdgcn_cvt_pkrtz(b[0], b[1]);
    u.h2[3] = __builtin_amdgcn_cvt_pkrtz(b[2], b[3]);
    ((f16x8*)xp)[t] = u.h8;
}

// ---------------- P1: S = X*Y^T - 0.5*|y|^2 — counted-vmcnt DMA pipeline ----------------
// y: global_load_lds f32 into 4-deep LDS ring (64KB -> 2 blocks/CU, 16 waves);
// A: L2 -> VGPR direct (r10 path, no LDS cost), double-buffered, issued BEFORE
// the y-DMA each iter so the af wait (vmcnt(8)) leaves y(ks+2),y(ks+3) in flight.
// vmcnt never drains to 0 mid-loop; sched_barrier(0) pins FIFO issue order.
__global__ __launch_bounds__(512, 4) void kqk(
    const f16* __restrict__ xp, const float* __restrict__ y,
    float* __restrict__ S, float* __restrict__ pmax) {
    __shared__ char Ys[4][16384];   // 64 rows x 256 B f32 per buf

    const int tid = threadIdx.x;
    const int blk = blockIdx.x;
    const int n0  = blk * 64;
    const int w = tid >> 6, l = tid & 63;
    const int l15 = l & 15, lg = l >> 4;

    // y DMA: pre-swizzled per-lane global src, linear LDS dest (both-sides rule)
    const char* ysrc[2];
    #pragma unroll
    for (int i = 0; i < 2; ++i) {
        int D = (((w << 1) + i) << 6) + l;
        int row = D >> 4, u = D & 15;
        int grow = n0 + row; grow = grow < NTR ? grow : NTR - 1;
        ysrc[i] = (const char*)y + (size_t)grow * (DD * 4) + ((u ^ (row & 7)) << 4);
    }
    auto stageY = [&](int ks) {
        #pragma unroll
        for (int i = 0; i < 2; ++i)
            gload_lds16(ysrc[i] + (ks << 8), &Ys[ks & 3][(((w << 1) + i) << 10)]);
    };

    const f16x8* ap = (const f16x8*)xp;
    const int arow = (w << 5) + l15;        // wave w owns query rows w*32..w*32+31
    auto loadA = [&](f16x8 (&af)[2][2], int ks) {
        #pragma unroll
        for (int kk = 0; kk < 2; ++kk)
            #pragma unroll
            for (int fm = 0; fm < 2; ++fm)
                af[kk][fm] = ap[(size_t)((ks << 3) + (kk << 2) + lg) * 256 + arow + (fm << 4)];
    };

    f32x4 acc[2][4] = {};
    float y2a[4] = {0.f, 0.f, 0.f, 0.f};
    f16x8 afP[2][2], afQ[2][2];

    // prologue: af(0) then y(0..2) — FIFO: af0 oldest
    loadA(afP, 0);
    __builtin_amdgcn_sched_barrier(0);
    stageY(0); stageY(1); stageY(2);
    __builtin_amdgcn_sched_barrier(0);

    auto ITER = [&](int ks, f16x8 (&CUR)[2][2], f16x8 (&NXT)[2][2]) {
        if (ks + 1 < 48) loadA(NXT, ks + 1);
        __builtin_amdgcn_sched_barrier(0);
        if (ks + 3 < 48) stageY(ks + 3);
        __builtin_amdgcn_sched_barrier(0);
        // counted wait: completes af(ks) (and y up to ks+1); never 0 mid-loop
        if (ks == 0)       asm volatile("s_waitcnt vmcnt(10)" ::: "memory");
        else if (ks <= 44) asm volatile("s_waitcnt vmcnt(8)"  ::: "memory");
        else if (ks == 45) asm volatile("s_waitcnt vmcnt(6)"  ::: "memory");
        else if (ks == 46) asm volatile("s_waitcnt vmcnt(4)"  ::: "memory");
        else               asm volatile("s_waitcnt vmcnt(0)"  ::: "memory");
        __builtin_amdgcn_s_barrier();   // all waves' y(ks) landed
        const char* Yc = Ys[ks & 3];
        #pragma unroll
        for (int kk = 0; kk < 2; ++kk) {
            f16x8 bf[4];
            #pragma unroll
            for (int fn = 0; fn < 4; ++fn) {
                const int row = (fn << 4) + l15;
                const int v0 = (kk << 3) + (lg << 1);
                f32x4 lo = *(const f32x4*)(Yc + (((row << 4) + (v0 ^ (row & 7))) << 4));
                f32x4 hi = *(const f32x4*)(Yc + (((row << 4) + ((v0 + 1) ^ (row & 7))) << 4));
                if (w == 0) {
                    y2a[fn] += lo[0]*lo[0] + lo[1]*lo[1] + lo[2]*lo[2] + lo[3]*lo[3]
                             + hi[0]*hi[0] + hi[1]*hi[1] + hi[2]*hi[2] + hi[3]*hi[3];
                }
                union { f16x2 h2[4]; f16x8 h8; } u;
                u.h2[0] = __builtin_amdgcn_cvt_pkrtz(lo[0], lo[1]);
                u.h2[1] = __builtin_amdgcn_cvt_pkrtz(lo[2], lo[3]);
                u.h2[2] = __builtin_amdgcn_cvt_pkrtz(hi[0], hi[1]);
                u.h2[3] = __builtin_amdgcn_cvt_pkrtz(hi[2], hi[3]);
                bf[fn] = u.h8;
            }
            #pragma unroll
            for (int fm = 0; fm < 2; ++fm)
                #pragma unroll
                for (int fn = 0; fn < 4; ++fn)
                    acc[fm][fn] = __builtin_amdgcn_mfma_f32_16x16x32_f16(CUR[kk][fm], bf[fn], acc[fm][fn], 0, 0, 0);
        }
        __builtin_amdgcn_s_barrier();   // reads done -> ring buffer may be overwritten
    };

    for (int ks2 = 0; ks2 < 48; ks2 += 2) {
        ITER(ks2,     afP, afQ);
        ITER(ks2 + 1, afQ, afP);
    }

    // epilogue: y2 (wave 0 holds full per-row sums across lg) -> LDS broadcast
    float* lys = (float*)&Ys[0][0];
    #pragma unroll
    for (int fn = 0; fn < 4; ++fn) {
        float v = y2a[fn];
        v += __shfl_xor(v, 16, 64);
        v += __shfl_xor(v, 32, 64);
        y2a[fn] = v;
    }
    if (w == 0 && lg == 0) {
        #pragma unroll
        for (int fn = 0; fn < 4; ++fn) lys[(fn << 4) + l15] = y2a[fn];
    }
    __syncthreads();
    float ly2[4];
    #pragma unroll
    for (int fn = 0; fn < 4; ++fn) ly2[fn] = 0.5f * lys[(fn << 4) + l15];
    // per-row max over this block's 64 cols (pad cols masked)
    #pragma unroll
    for (int fm = 0; fm < 2; ++fm) {
        #pragma unroll
        for (int j = 0; j < 4; ++j) {
            float rm = -3.4e38f;
            #pragma unroll
            for (int fn = 0; fn < 4; ++fn) {
                int col = n0 + (fn << 4) + l15;
                float sc = acc[fm][fn][j] - ly2[fn];
                rm = (col < NTR) ? fmaxf(rm, sc) : rm;
            }
            #pragma unroll
            for (int off = 1; off < 16; off <<= 1) rm = fmaxf(rm, __shfl_xor(rm, off, 64));
            if (l15 == 0)
                pmax[(size_t)((w << 5) + (fm << 4) + (lg << 2) + j) * NBLK + blk] = rm;
        }
    }
    // S = x.y - 0.5|y|^2
    #pragma unroll
    for (int fm = 0; fm < 2; ++fm) {
        int row0 = (w << 5) + (fm << 4) + (lg << 2);
        #pragma unroll
        for (int fn = 0; fn < 4; ++fn) {
            int col = n0 + (fn << 4) + l15;
            float* sp = S + (size_t)row0 * NSP + col;
            sp[0]               = acc[fm][fn][0] - ly2[fn];
            sp[NSP]             = acc[fm][fn][1] - ly2[fn];
            sp[2 * (size_t)NSP] = acc[fm][fn][2] - ly2[fn];
            sp[3 * (size_t)NSP] = acc[fm][fn][3] - ly2[fn];
        }
    }
}

// ---------------- P2: row max from pmax + candidate selection ----------------
__global__ __launch_bounds__(256) void ksel(
    const float* __restrict__ S, const float* __restrict__ pmax,
    const float* __restrict__ sig, unsigned* __restrict__ cnt,
    unsigned* __restrict__ cand) {
    __shared__ float red[4];
    const int b = blockIdx.x, tid = threadIdx.x;
    const float s2 = sig[b] * sig[b];
    const float* pm = pmax + (size_t)b * NBLK;
    float mx = -3.4e38f;
    for (int i = tid; i < NBLK; i += 256) mx = fmaxf(mx, pm[i]);
    #pragma unroll
    for (int o = 1; o < 64; o <<= 1) mx = fmaxf(mx, __shfl_xor(mx, o, 64));
    if ((tid & 63) == 0) red[tid >> 6] = mx;
    __syncthreads();
    mx = fmaxf(fmaxf(red[0], red[1]), fmaxf(red[2], red[3]));
    const float thr = mx - DELTA * s2;
    const f32x4* rowv = (const f32x4*)(S + (size_t)b * NSP);
    for (int i = tid; i < 12500; i += 256) {
        f32x4 s = rowv[i];
        #pragma unroll
        for (int j = 0; j < 4; ++j) {
            if (s[j] >= thr) {
                unsigned idx = atomicAdd(&cnt[b], 1u);
                if (idx < CAP) cand[(size_t)b * CAP + idx] = (unsigned)(4 * i + j);
            }
        }
    }
}

// ---------------- P3: fused exact rescoring + online softmax + PV ----------------
__global__ __launch_bounds__(512) void kpv(
    const float* __restrict__ x, const float* __restrict__ y,
    const float* __restrict__ sig, const unsigned* __restrict__ cnt,
    const unsigned* __restrict__ cand, float* __restrict__ out) {
    __shared__ float xs[DD];
    __shared__ unsigned ci[CAP];
    __shared__ float om[8], ol[8];
    __shared__ float sumv[DD];
    const int b = blockIdx.x, tid = threadIdx.x;
    const int c = (int)(cnt[b] < (unsigned)CAP ? cnt[b] : (unsigned)CAP);
    const float s2 = sig[b] * sig[b];
    const float isc = -0.5f / s2;
    for (int i = tid; i < DD; i += 512) xs[i] = x[(size_t)b * DD + i];
    for (int i = tid; i < c; i += 512) ci[i] = cand[(size_t)b * CAP + i];
    __syncthreads();
    const int w = tid >> 6, l = tid & 63;
    const f32x4* xr = (const f32x4*)xs;

    f32x4 o[12] = {};
    float m = -3.4e38f, ll = 0.f;
    f32x4 A[12], Bv[12];

    auto LD = [&](f32x4* dst, int i) {
        const f32x4* yr = (const f32x4*)(y + (size_t)ci[i] * DD);
        #pragma unroll
        for (int j = 0; j < 12; ++j) dst[j] = yr[(j << 6) + l];
    };
    auto PROC = [&](f32x4* src) {
        float d2 = 0.f;
        #pragma unroll
        for (int j = 0; j < 12; ++j) {
            f32x4 xv = xr[(j << 6) + l];
            float a0 = xv[0]-src[j][0], a1 = xv[1]-src[j][1],
                  a2 = xv[2]-src[j][2], a3 = xv[3]-src[j][3];
            d2 += a0*a0 + a1*a1 + a2*a2 + a3*a3;
        }
        #pragma unroll
        for (int off = 1; off < 64; off <<= 1) d2 += __shfl_xor(d2, off, 64);
        float s = d2 * isc;
        float mn = fmaxf(m, s);
        float f = __expf(m - mn);
        float wi = __expf(s - mn);
        #pragma unroll
        for (int j = 0; j < 12; ++j) o[j] = o[j] * f + wi * src[j];
        ll = ll * f + wi;
        m = mn;
    };

    int i = w;
    if (i < c) LD(A, i);
    for (; i < c; i += 16) {
        int i2 = i + 8;
        if (i2 < c) LD(Bv, i2);
        PROC(A);
        if (i2 < c) {
            if (i + 16 < c) LD(A, i + 16);
            PROC(Bv);
        }
    }
    om[w] = m; ol[w] = ll;
    __syncthreads();
    float M = om[0];
    #pragma unroll
    for (int ww = 1; ww < 8; ++ww) M = fmaxf(M, om[ww]);
    float Ls = 0.f;
    #pragma unroll
    for (int ww = 0; ww < 8; ++ww) Ls += ol[ww] * __expf(om[ww] - M);
    const float fw = __expf(m - M);
    f32x4* sv = (f32x4*)sumv;
    if (w == 0) {
        #pragma unroll
        for (int j = 0; j < 12; ++j) sv[(j << 6) + l] = o[j] * fw;
    }
    __syncthreads();
    for (int ww = 1; ww < 8; ++ww) {
        if (w == ww) {
            #pragma unroll
            for (int j = 0; j < 12; ++j) sv[(j << 6) + l] += o[j] * fw;
        }
        __syncthreads();
    }
    const float inv = 1.f / Ls;
    f32x4* od = (f32x4*)(out + (size_t)b * DD);
    for (int t = tid; t < 768; t += 512) od[t] = sv[t] * inv;
}

extern "C" void kernel_launch(void* const* d_in, const int* in_sizes, int n_in,
                              void* d_out, int out_size, void* d_ws, size_t ws_size,
                              hipStream_t stream) {
    const float* x   = (const float*)d_in[0];
    const float* sig = (const float*)d_in[1];
    const float* y   = (const float*)d_in[2];
    float* out = (float*)d_out;
    char* ws = (char*)d_ws;
    f16*      xp   = (f16*)(ws);                  // 1,572,864
    unsigned* cnt  = (unsigned*)(ws + 1572864);   // 1,024
    unsigned* cand = (unsigned*)(ws + 1573888);   // 4,194,304
    float*    pmax = (float*)(ws + 5768192);      // 256*782*4 = 800,768
    float*    S    = (float*)(ws + 6568960);      // 256*50048*4 = 51,249,152

    (void)hipMemsetAsync(cnt, 0, 256 * sizeof(unsigned), stream);
    kx  <<<384, 256, 0, stream>>>(x, xp);
    kqk <<<NBLK, 512, 0, stream>>>(xp, y, S, pmax);
    ksel<<<256, 256, 0, stream>>>(S, pmax, sig, cnt, cand);
    kpv <<<256, 512, 0, stream>>>(x, y, sig, cnt, cand, out);
}

// Round 15
// 245.878 us; speedup vs baseline: 1.7404x; 1.4704x over previous
//
#include <hip/hip_runtime.h>
#include <hip/hip_bf16.h>
#include <type_traits>

#define BQ   256
#define NTR  50000
#define DD   3072
#define NSP  50048          // padded N stride (multiple of 64)
#define NBLK 782
#define CAP  4096
#define DELTA 18.0f

typedef __fp16 f16;
typedef __fp16 f16x2 __attribute__((ext_vector_type(2)));
typedef __fp16 f16x8 __attribute__((ext_vector_type(8)));
typedef float  f32x4 __attribute__((ext_vector_type(4)));

// ---------------- P0: convert x (f32) -> fp16, fragment-major pack ----------------
__global__ __launch_bounds__(256) void kx(const float* __restrict__ x, f16* __restrict__ xp) {
    const int t = blockIdx.x * 256 + threadIdx.x;   // t = g*256 + r, grid = 384*256
    const int g = t >> 8, r = t & 255;
    const f32x4* src = (const f32x4*)(x + (size_t)r * DD + (g << 3));
    f32x4 a = src[0], b = src[1];
    union { f16x2 h2[4]; f16x8 h8; } u;
    u.h2[0] = __builtin_amdgcn_cvt_pkrtz(a[0], a[1]);
    u.h2[1] = __builtin_amdgcn_cvt_pkrtz(a[2], a[3]);
    u.h2[2] = __builtin_amdgcn_cvt_pkrtz(b[0], b[1]);
    u.h2[3] = __builtin_amdgcn_cvt_pkrtz(b[2], b[3]);
    ((f16x8*)xp)[t] = u.h8;
}

// ---------------- P1: S = X*Y^T - 0.5*|y|^2 (r10-exact structure; S stored fp16) ----------------
__global__ __launch_bounds__(512, 4) void kqk(
    const f16* __restrict__ xp, const float* __restrict__ y,
    f16* __restrict__ S, float* __restrict__ pmax) {
    __shared__ char Bs[2][8192];   // 64 rows x 128 B (fp16), XOR-swizzled

    const int tid = threadIdx.x;
    const int blk = blockIdx.x;
    const int n0  = blk * 64;

    // y staging: 8 threads per row, each 8 consecutive f32 (32 B)
    const int ry   = tid >> 3;            // 0..63
    const int kp   = (tid & 7) << 3;      // f32 offset 0..56
    const int yrow = n0 + ry;
    const bool yval = yrow < NTR;
    const float* ybase = y + (size_t)yrow * DD + kp;
    const int bo = ry * 128 + ((((tid & 7) << 4)) ^ ((ry & 7) << 4));

    const int w = tid >> 6, l = tid & 63;   // w = 0..7
    const int l15 = l & 15, lg = l >> 4;

    f32x4 acc[2][4] = {};
    float y2a = 0.f;
    f32x4 p0, p1, q0, q1;

    auto loady = [&](f32x4& a0, f32x4& a1, int ks) {
        if (yval) {
            const f32x4* pp = (const f32x4*)(ybase + (ks << 6));
            a0 = pp[0]; a1 = pp[1];
        } else { a0 = 0.f; a1 = 0.f; }
    };
    auto cvtw = [&](f32x4& a0, f32x4& a1, int buf) {
        y2a += a0[0]*a0[0] + a0[1]*a0[1] + a0[2]*a0[2] + a0[3]*a0[3]
             + a1[0]*a1[0] + a1[1]*a1[1] + a1[2]*a1[2] + a1[3]*a1[3];
        union { f16x2 h2[4]; f16x8 h8; } u;
        u.h2[0] = __builtin_amdgcn_cvt_pkrtz(a0[0], a0[1]);
        u.h2[1] = __builtin_amdgcn_cvt_pkrtz(a0[2], a0[3]);
        u.h2[2] = __builtin_amdgcn_cvt_pkrtz(a1[0], a1[1]);
        u.h2[3] = __builtin_amdgcn_cvt_pkrtz(a1[2], a1[3]);
        *(f16x8*)(&Bs[buf][bo]) = u.h8;
    };

    // prologue: y(0)->Bs[0], y(1) in Q
    loady(p0, p1, 0);
    loady(q0, q1, 1);
    cvtw(p0, p1, 0);
    asm volatile("s_waitcnt lgkmcnt(0)" ::: "memory");
    __builtin_amdgcn_s_barrier();

    const f16x8* ap = (const f16x8*)xp;
    const int arow = (w << 5) + l15;        // wave w owns query rows w*32..w*32+31

    auto iter = [&](int ks, auto curC,
                    f32x4& s0, f32x4& s1,      // prefetch slot (y(ks+2))
                    f32x4& t0, f32x4& t1) {    // cvt slot (y(ks+1))
        constexpr int cur = decltype(curC)::value;
        f16x8 af[2][2];
        #pragma unroll
        for (int kk = 0; kk < 2; ++kk)
            #pragma unroll
            for (int fm = 0; fm < 2; ++fm)
                af[kk][fm] = ap[(size_t)((ks << 3) + (kk << 2) + lg) * 256 + arow + (fm << 4)];
        if (ks + 2 < 48) loady(s0, s1, ks + 2);
        f16x8 bf[2][4];
        #pragma unroll
        for (int kk = 0; kk < 2; ++kk)
            #pragma unroll
            for (int fn = 0; fn < 4; ++fn) {
                int r = (fn << 4) + l15;
                bf[kk][fn] = *(const f16x8*)(&Bs[cur][r * 128 + (((kk << 6) + (lg << 4)) ^ ((r & 7) << 4))]);
            }
        #pragma unroll
        for (int kk = 0; kk < 2; ++kk)
            #pragma unroll
            for (int fm = 0; fm < 2; ++fm)
                #pragma unroll
                for (int fn = 0; fn < 4; ++fn)
                    acc[fm][fn] = __builtin_amdgcn_mfma_f32_16x16x32_f16(af[kk][fm], bf[kk][fn], acc[fm][fn], 0, 0, 0);
        if (ks + 1 < 48) cvtw(t0, t1, cur ^ 1);
        asm volatile("s_waitcnt lgkmcnt(0)" ::: "memory");
        __builtin_amdgcn_s_barrier();
    };

    for (int ks2 = 0; ks2 < 48; ks2 += 2) {
        iter(ks2,     std::integral_constant<int,0>{}, p0, p1, q0, q1);
        iter(ks2 + 1, std::integral_constant<int,1>{}, q0, q1, p0, p1);
    }

    // epilogue: y2 per row (8 threads/row) -> LDS broadcast
    float* lys = (float*)&Bs[0][0];
    y2a += __shfl_xor(y2a, 1, 64);
    y2a += __shfl_xor(y2a, 2, 64);
    y2a += __shfl_xor(y2a, 4, 64);
    if ((tid & 7) == 0) lys[ry] = y2a;
    __syncthreads();
    float ly2[4];
    #pragma unroll
    for (int fn = 0; fn < 4; ++fn) ly2[fn] = 0.5f * lys[(fn << 4) + l15];
    // per-row max over this block's 64 cols (pad cols masked)
    #pragma unroll
    for (int fm = 0; fm < 2; ++fm) {
        #pragma unroll
        for (int j = 0; j < 4; ++j) {
            float rm = -3.4e38f;
            #pragma unroll
            for (int fn = 0; fn < 4; ++fn) {
                int col = n0 + (fn << 4) + l15;
                float sc = acc[fm][fn][j] - ly2[fn];
                rm = (col < NTR) ? fmaxf(rm, sc) : rm;
            }
            #pragma unroll
            for (int off = 1; off < 16; off <<= 1) rm = fmaxf(rm, __shfl_xor(rm, off, 64));
            if (l15 == 0)
                pmax[(size_t)((w << 5) + (fm << 4) + (lg << 2) + j) * NBLK + blk] = rm;
        }
    }
    // S = x.y - 0.5|y|^2, stored fp16 (selection-only; exact rescore happens in ksp)
    #pragma unroll
    for (int fm = 0; fm < 2; ++fm) {
        int row0 = (w << 5) + (fm << 4) + (lg << 2);
        #pragma unroll
        for (int fn = 0; fn < 4; ++fn) {
            int col = n0 + (fn << 4) + l15;
            f16* sp = S + (size_t)row0 * NSP + col;
            sp[0]               = (f16)(acc[fm][fn][0] - ly2[fn]);
            sp[NSP]             = (f16)(acc[fm][fn][1] - ly2[fn]);
            sp[2 * (size_t)NSP] = (f16)(acc[fm][fn][2] - ly2[fn]);
            sp[3 * (size_t)NSP] = (f16)(acc[fm][fn][3] - ly2[fn]);
        }
    }
}

// ---------------- P2+P3 fused: max -> scan fp16 S -> exact rescore + online softmax + PV ----------------
__global__ __launch_bounds__(512) void ksp(
    const float* __restrict__ x, const float* __restrict__ y,
    const f16* __restrict__ S, const float* __restrict__ pmax,
    const float* __restrict__ sig, float* __restrict__ out) {
    __shared__ float xs[DD];
    __shared__ unsigned ci[CAP];
    __shared__ unsigned scnt;
    __shared__ float red[8];
    __shared__ float om[8], ol[8];
    __shared__ float sumv[DD];
    const int b = blockIdx.x, tid = threadIdx.x;
    const float s2 = sig[b] * sig[b];
    const float isc = -0.5f / s2;
    const int w = tid >> 6, l = tid & 63;

    if (tid == 0) scnt = 0;
    for (int i = tid; i < DD; i += 512) xs[i] = x[(size_t)b * DD + i];
    // phase a: row max from pmax (exact f32)
    const float* pm = pmax + (size_t)b * NBLK;
    float mx = -3.4e38f;
    for (int i = tid; i < NBLK; i += 512) mx = fmaxf(mx, pm[i]);
    #pragma unroll
    for (int o = 1; o < 64; o <<= 1) mx = fmaxf(mx, __shfl_xor(mx, o, 64));
    if (l == 0) red[w] = mx;
    __syncthreads();
    mx = red[0];
    #pragma unroll
    for (int ww = 1; ww < 8; ++ww) mx = fmaxf(mx, red[ww]);
    // fp16-S safety margin 2.0: top candidates can't be dropped by quantization
    const float thr = mx - DELTA * s2 - 2.0f;

    // phase b: scan fp16 S row, candidates -> LDS
    const f16x8* row = (const f16x8*)(S + (size_t)b * NSP);
    for (int i = tid; i < 6256; i += 512) {      // 6256*8 = 50048
        f16x8 v = row[i];
        #pragma unroll
        for (int j = 0; j < 8; ++j) {
            int idx = (i << 3) + j;
            if ((float)v[j] >= thr && idx < NTR) {
                unsigned p = atomicAdd(&scnt, 1u);
                if (p < CAP) ci[p] = (unsigned)idx;
            }
        }
    }
    __syncthreads();
    const int c = (int)(scnt < (unsigned)CAP ? scnt : (unsigned)CAP);

    // phase c: exact rescoring + online softmax + PV (one pass over candidate rows)
    const f32x4* xr = (const f32x4*)xs;
    f32x4 o[12] = {};
    float m = -3.4e38f, ll = 0.f;
    f32x4 A[12], Bv[12];

    auto LD = [&](f32x4* dst, int i) {
        const f32x4* yr = (const f32x4*)(y + (size_t)ci[i] * DD);
        #pragma unroll
        for (int j = 0; j < 12; ++j) dst[j] = yr[(j << 6) + l];
    };
    auto PROC = [&](f32x4* src) {
        float d2 = 0.f;
        #pragma unroll
        for (int j = 0; j < 12; ++j) {
            f32x4 xv = xr[(j << 6) + l];
            float a0 = xv[0]-src[j][0], a1 = xv[1]-src[j][1],
                  a2 = xv[2]-src[j][2], a3 = xv[3]-src[j][3];
            d2 += a0*a0 + a1*a1 + a2*a2 + a3*a3;
        }
        #pragma unroll
        for (int off = 1; off < 64; off <<= 1) d2 += __shfl_xor(d2, off, 64);
        float s = d2 * isc;
        float mn = fmaxf(m, s);
        float f = __expf(m - mn);
        float wi = __expf(s - mn);
        #pragma unroll
        for (int j = 0; j < 12; ++j) o[j] = o[j] * f + wi * src[j];
        ll = ll * f + wi;
        m = mn;
    };

    int i = w;
    if (i < c) LD(A, i);
    for (; i < c; i += 16) {
        int i2 = i + 8;
        if (i2 < c) LD(Bv, i2);
        PROC(A);
        if (i2 < c) {
            if (i + 16 < c) LD(A, i + 16);
            PROC(Bv);
        }
    }
    om[w] = m; ol[w] = ll;
    __syncthreads();
    float M = om[0];
    #pragma unroll
    for (int ww = 1; ww < 8; ++ww) M = fmaxf(M, om[ww]);
    float Ls = 0.f;
    #pragma unroll
    for (int ww = 0; ww < 8; ++ww) Ls += ol[ww] * __expf(om[ww] - M);
    const float fw = __expf(m - M);
    f32x4* sv = (f32x4*)sumv;
    if (w == 0) {
        #pragma unroll
        for (int j = 0; j < 12; ++j) sv[(j << 6) + l] = o[j] * fw;
    }
    __syncthreads();
    for (int ww = 1; ww < 8; ++ww) {
        if (w == ww) {
            #pragma unroll
            for (int j = 0; j < 12; ++j) sv[(j << 6) + l] += o[j] * fw;
        }
        __syncthreads();
    }
    const float inv = 1.f / Ls;
    f32x4* od = (f32x4*)(out + (size_t)b * DD);
    for (int t = tid; t < 768; t += 512) od[t] = sv[t] * inv;
}

extern "C" void kernel_launch(void* const* d_in, const int* in_sizes, int n_in,
                              void* d_out, int out_size, void* d_ws, size_t ws_size,
                              hipStream_t stream) {
    const float* x   = (const float*)d_in[0];
    const float* sig = (const float*)d_in[1];
    const float* y   = (const float*)d_in[2];
    float* out = (float*)d_out;
    char* ws = (char*)d_ws;
    f16*   xp   = (f16*)(ws);                   // 1,572,864
    float* pmax = (float*)(ws + 1572864);       // 256*782*4 = 800,768
    f16*   S    = (f16*)(ws + 2373632);         // 256*50048*2 = 25,624,576

    kx  <<<384, 256, 0, stream>>>(x, xp);
    kqk <<<NBLK, 512, 0, stream>>>(xp, y, S, pmax);
    ksp <<<256, 512, 0, stream>>>(x, y, S, pmax, sig, out);
}

// Round 16
// 243.497 us; speedup vs baseline: 1.7574x; 1.0098x over previous
//
#include <hip/hip_runtime.h>
#include <hip/hip_bf16.h>
#include <type_traits>

#define BQ   256
#define NTR  50000
#define DD   3072
#define NSP  50048          // padded N stride (multiple of 64)
#define NBLK 782
#define CAP  4096
#define DELTA 18.0f

typedef __fp16 f16;
typedef __fp16 f16x2 __attribute__((ext_vector_type(2)));
typedef __fp16 f16x4 __attribute__((ext_vector_type(4)));
typedef __fp16 f16x8 __attribute__((ext_vector_type(8)));
typedef float  f32x4 __attribute__((ext_vector_type(4)));

// ---------------- P0: convert x (f32) -> fp16, fragment-major pack ----------------
__global__ __launch_bounds__(256) void kx(const float* __restrict__ x, f16* __restrict__ xp) {
    const int t = blockIdx.x * 256 + threadIdx.x;   // t = g*256 + r, grid = 384*256
    const int g = t >> 8, r = t & 255;
    const f32x4* src = (const f32x4*)(x + (size_t)r * DD + (g << 3));
    f32x4 a = src[0], b = src[1];
    union { f16x2 h2[4]; f16x8 h8; } u;
    u.h2[0] = __builtin_amdgcn_cvt_pkrtz(a[0], a[1]);
    u.h2[1] = __builtin_amdgcn_cvt_pkrtz(a[2], a[3]);
    u.h2[2] = __builtin_amdgcn_cvt_pkrtz(b[0], b[1]);
    u.h2[3] = __builtin_amdgcn_cvt_pkrtz(b[2], b[3]);
    ((f16x8*)xp)[t] = u.h8;
}

// ---------------- P1: S = X*Y^T - 0.5*|y|^2 (fp16 S; 256B/row DRAM grain + XCD swizzle) ----------------
// y staging: 16 threads/row x 16B -> each wave-instruction reads 4 rows x 256B
// CONTIGUOUS (2x r10's 128B grain; fewer DRAM row activates). Each thread covers
// rows ry0 and ry0+32. XCD-chunked block swizzle (bijective): each XCD's L2 sees
// one contiguous ~77MB y-region. Pipeline skeleton identical to r10/r15.
__global__ __launch_bounds__(512, 4) void kqk(
    const f16* __restrict__ xp, const float* __restrict__ y,
    f16* __restrict__ S, float* __restrict__ pmax) {
    __shared__ char Bs[2][8192];   // 64 rows x 128 B (fp16), XOR-swizzled

    const int tid = threadIdx.x;
    // XCD-chunked bijective swizzle (782 = 6*98 + 2*97)
    const int orig = blockIdx.x;
    const int xcd = orig & 7, cidx = orig >> 3;
    const int blk = (xcd < 6 ? xcd * 98 : 588 + (xcd - 6) * 97) + cidx;
    const int n0  = blk * 64;

    // y staging: 16 threads/row, 16B each; thread covers rows ry0 and ry0+32
    const int ry0 = tid >> 4;             // 0..31
    const int kc  = tid & 15;             // 16B chunk within the 256B row-step
    const int yr0 = n0 + ry0, yr1 = yr0 + 32;
    const bool yv0 = yr0 < NTR, yv1 = yr1 < NTR;
    const float* yb0 = y + (size_t)yr0 * DD + (kc << 2);
    const float* yb1 = y + (size_t)yr1 * DD + (kc << 2);
    const int swz = (ry0 & 7) << 4;       // (ry0+32)&7 == ry0&7
    const int bo0 = ry0 * 128        + (((((kc >> 1) << 4)) ^ swz) | ((kc & 1) << 3));
    const int bo1 = (ry0 + 32) * 128 + (((((kc >> 1) << 4)) ^ swz) | ((kc & 1) << 3));

    const int w = tid >> 6, l = tid & 63;   // w = 0..7
    const int l15 = l & 15, lg = l >> 4;

    f32x4 acc[2][4] = {};
    float y2a0 = 0.f, y2a1 = 0.f;
    f32x4 p0, p1, q0, q1;

    auto loady = [&](f32x4& a0, f32x4& a1, int ks) {
        a0 = yv0 ? *(const f32x4*)(yb0 + (ks << 6)) : f32x4(0.f);
        a1 = yv1 ? *(const f32x4*)(yb1 + (ks << 6)) : f32x4(0.f);
    };
    auto cvtw = [&](f32x4& a0, f32x4& a1, int buf) {
        y2a0 += a0[0]*a0[0] + a0[1]*a0[1] + a0[2]*a0[2] + a0[3]*a0[3];
        y2a1 += a1[0]*a1[0] + a1[1]*a1[1] + a1[2]*a1[2] + a1[3]*a1[3];
        union { f16x2 h2[2]; f16x4 h4; } u0, u1;
        u0.h2[0] = __builtin_amdgcn_cvt_pkrtz(a0[0], a0[1]);
        u0.h2[1] = __builtin_amdgcn_cvt_pkrtz(a0[2], a0[3]);
        u1.h2[0] = __builtin_amdgcn_cvt_pkrtz(a1[0], a1[1]);
        u1.h2[1] = __builtin_amdgcn_cvt_pkrtz(a1[2], a1[3]);
        *(f16x4*)(&Bs[buf][bo0]) = u0.h4;
        *(f16x4*)(&Bs[buf][bo1]) = u1.h4;
    };

    // prologue: y(0)->Bs[0], y(1) in Q
    loady(p0, p1, 0);
    loady(q0, q1, 1);
    cvtw(p0, p1, 0);
    asm volatile("s_waitcnt lgkmcnt(0)" ::: "memory");
    __builtin_amdgcn_s_barrier();

    const f16x8* ap = (const f16x8*)xp;
    const int arow = (w << 5) + l15;        // wave w owns query rows w*32..w*32+31

    auto iter = [&](int ks, auto curC,
                    f32x4& s0, f32x4& s1,      // prefetch slot (y(ks+2))
                    f32x4& t0, f32x4& t1) {    // cvt slot (y(ks+1))
        constexpr int cur = decltype(curC)::value;
        f16x8 af[2][2];
        #pragma unroll
        for (int kk = 0; kk < 2; ++kk)
            #pragma unroll
            for (int fm = 0; fm < 2; ++fm)
                af[kk][fm] = ap[(size_t)((ks << 3) + (kk << 2) + lg) * 256 + arow + (fm << 4)];
        if (ks + 2 < 48) loady(s0, s1, ks + 2);
        f16x8 bf[2][4];
        #pragma unroll
        for (int kk = 0; kk < 2; ++kk)
            #pragma unroll
            for (int fn = 0; fn < 4; ++fn) {
                int r = (fn << 4) + l15;
                bf[kk][fn] = *(const f16x8*)(&Bs[cur][r * 128 + (((kk << 6) + (lg << 4)) ^ ((r & 7) << 4))]);
            }
        #pragma unroll
        for (int kk = 0; kk < 2; ++kk)
            #pragma unroll
            for (int fm = 0; fm < 2; ++fm)
                #pragma unroll
                for (int fn = 0; fn < 4; ++fn)
                    acc[fm][fn] = __builtin_amdgcn_mfma_f32_16x16x32_f16(af[kk][fm], bf[kk][fn], acc[fm][fn], 0, 0, 0);
        if (ks + 1 < 48) cvtw(t0, t1, cur ^ 1);
        asm volatile("s_waitcnt lgkmcnt(0)" ::: "memory");
        __builtin_amdgcn_s_barrier();
    };

    for (int ks2 = 0; ks2 < 48; ks2 += 2) {
        iter(ks2,     std::integral_constant<int,0>{}, p0, p1, q0, q1);
        iter(ks2 + 1, std::integral_constant<int,1>{}, q0, q1, p0, p1);
    }

    // epilogue: y2 per row (16 threads/row, 2 rows/thread) -> LDS broadcast
    float* lys = (float*)&Bs[0][0];
    #pragma unroll
    for (int off = 1; off < 16; off <<= 1) {
        y2a0 += __shfl_xor(y2a0, off, 64);
        y2a1 += __shfl_xor(y2a1, off, 64);
    }
    if ((tid & 15) == 0) { lys[ry0] = y2a0; lys[ry0 + 32] = y2a1; }
    __syncthreads();
    float ly2[4];
    #pragma unroll
    for (int fn = 0; fn < 4; ++fn) ly2[fn] = 0.5f * lys[(fn << 4) + l15];
    // per-row max over this block's 64 cols (pad cols masked)
    #pragma unroll
    for (int fm = 0; fm < 2; ++fm) {
        #pragma unroll
        for (int j = 0; j < 4; ++j) {
            float rm = -3.4e38f;
            #pragma unroll
            for (int fn = 0; fn < 4; ++fn) {
                int col = n0 + (fn << 4) + l15;
                float sc = acc[fm][fn][j] - ly2[fn];
                rm = (col < NTR) ? fmaxf(rm, sc) : rm;
            }
            #pragma unroll
            for (int off = 1; off < 16; off <<= 1) rm = fmaxf(rm, __shfl_xor(rm, off, 64));
            if (l15 == 0)
                pmax[(size_t)((w << 5) + (fm << 4) + (lg << 2) + j) * NBLK + blk] = rm;
        }
    }
    // S = x.y - 0.5|y|^2, stored fp16 (selection-only; exact rescore happens in ksp)
    #pragma unroll
    for (int fm = 0; fm < 2; ++fm) {
        int row0 = (w << 5) + (fm << 4) + (lg << 2);
        #pragma unroll
        for (int fn = 0; fn < 4; ++fn) {
            int col = n0 + (fn << 4) + l15;
            f16* sp = S + (size_t)row0 * NSP + col;
            sp[0]               = (f16)(acc[fm][fn][0] - ly2[fn]);
            sp[NSP]             = (f16)(acc[fm][fn][1] - ly2[fn]);
            sp[2 * (size_t)NSP] = (f16)(acc[fm][fn][2] - ly2[fn]);
            sp[3 * (size_t)NSP] = (f16)(acc[fm][fn][3] - ly2[fn]);
        }
    }
}

// ---------------- P2+P3 fused: max -> scan fp16 S -> exact rescore + online softmax + PV ----------------
__global__ __launch_bounds__(512) void ksp(
    const float* __restrict__ x, const float* __restrict__ y,
    const f16* __restrict__ S, const float* __restrict__ pmax,
    const float* __restrict__ sig, float* __restrict__ out) {
    __shared__ float xs[DD];
    __shared__ unsigned ci[CAP];
    __shared__ unsigned scnt;
    __shared__ float red[8];
    __shared__ float om[8], ol[8];
    __shared__ float sumv[DD];
    const int b = blockIdx.x, tid = threadIdx.x;
    const float s2 = sig[b] * sig[b];
    const float isc = -0.5f / s2;
    const int w = tid >> 6, l = tid & 63;

    if (tid == 0) scnt = 0;
    for (int i = tid; i < DD; i += 512) xs[i] = x[(size_t)b * DD + i];
    // phase a: row max from pmax (exact f32)
    const float* pm = pmax + (size_t)b * NBLK;
    float mx = -3.4e38f;
    for (int i = tid; i < NBLK; i += 512) mx = fmaxf(mx, pm[i]);
    #pragma unroll
    for (int o = 1; o < 64; o <<= 1) mx = fmaxf(mx, __shfl_xor(mx, o, 64));
    if (l == 0) red[w] = mx;
    __syncthreads();
    mx = red[0];
    #pragma unroll
    for (int ww = 1; ww < 8; ++ww) mx = fmaxf(mx, red[ww]);
    // fp16-S safety margin 2.0: top candidates can't be dropped by quantization
    const float thr = mx - DELTA * s2 - 2.0f;

    // phase b: scan fp16 S row, candidates -> LDS
    const f16x8* row = (const f16x8*)(S + (size_t)b * NSP);
    for (int i = tid; i < 6256; i += 512) {      // 6256*8 = 50048
        f16x8 v = row[i];
        #pragma unroll
        for (int j = 0; j < 8; ++j) {
            int idx = (i << 3) + j;
            if ((float)v[j] >= thr && idx < NTR) {
                unsigned p = atomicAdd(&scnt, 1u);
                if (p < CAP) ci[p] = (unsigned)idx;
            }
        }
    }
    __syncthreads();
    const int c = (int)(scnt < (unsigned)CAP ? scnt : (unsigned)CAP);

    // phase c: exact rescoring + online softmax + PV (one pass over candidate rows)
    const f32x4* xr = (const f32x4*)xs;
    f32x4 o[12] = {};
    float m = -3.4e38f, ll = 0.f;
    f32x4 A[12], Bv[12];

    auto LD = [&](f32x4* dst, int i) {
        const f32x4* yr = (const f32x4*)(y + (size_t)ci[i] * DD);
        #pragma unroll
        for (int j = 0; j < 12; ++j) dst[j] = yr[(j << 6) + l];
    };
    auto PROC = [&](f32x4* src) {
        float d2 = 0.f;
        #pragma unroll
        for (int j = 0; j < 12; ++j) {
            f32x4 xv = xr[(j << 6) + l];
            float a0 = xv[0]-src[j][0], a1 = xv[1]-src[j][1],
                  a2 = xv[2]-src[j][2], a3 = xv[3]-src[j][3];
            d2 += a0*a0 + a1*a1 + a2*a2 + a3*a3;
        }
        #pragma unroll
        for (int off = 1; off < 64; off <<= 1) d2 += __shfl_xor(d2, off, 64);
        float s = d2 * isc;
        float mn = fmaxf(m, s);
        float f = __expf(m - mn);
        float wi = __expf(s - mn);
        #pragma unroll
        for (int j = 0; j < 12; ++j) o[j] = o[j] * f + wi * src[j];
        ll = ll * f + wi;
        m = mn;
    };

    int i = w;
    if (i < c) LD(A, i);
    for (; i < c; i += 16) {
        int i2 = i + 8;
        if (i2 < c) LD(Bv, i2);
        PROC(A);
        if (i2 < c) {
            if (i + 16 < c) LD(A, i + 16);
            PROC(Bv);
        }
    }
    om[w] = m; ol[w] = ll;
    __syncthreads();
    float M = om[0];
    #pragma unroll
    for (int ww = 1; ww < 8; ++ww) M = fmaxf(M, om[ww]);
    float Ls = 0.f;
    #pragma unroll
    for (int ww = 0; ww < 8; ++ww) Ls += ol[ww] * __expf(om[ww] - M);
    const float fw = __expf(m - M);
    f32x4* sv = (f32x4*)sumv;
    if (w == 0) {
        #pragma unroll
        for (int j = 0; j < 12; ++j) sv[(j << 6) + l] = o[j] * fw;
    }
    __syncthreads();
    for (int ww = 1; ww < 8; ++ww) {
        if (w == ww) {
            #pragma unroll
            for (int j = 0; j < 12; ++j) sv[(j << 6) + l] += o[j] * fw;
        }
        __syncthreads();
    }
    const float inv = 1.f / Ls;
    f32x4* od = (f32x4*)(out + (size_t)b * DD);
    for (int t = tid; t < 768; t += 512) od[t] = sv[t] * inv;
}

extern "C" void kernel_launch(void* const* d_in, const int* in_sizes, int n_in,
                              void* d_out, int out_size, void* d_ws, size_t ws_size,
                              hipStream_t stream) {
    const float* x   = (const float*)d_in[0];
    const float* sig = (const float*)d_in[1];
    const float* y   = (const float*)d_in[2];
    float* out = (float*)d_out;
    char* ws = (char*)d_ws;
    f16*   xp   = (f16*)(ws);                   // 1,572,864
    float* pmax = (float*)(ws + 1572864);       // 256*782*4 = 800,768
    f16*   S    = (f16*)(ws + 2373632);         // 256*50048*2 = 25,624,576

    kx  <<<384, 256, 0, stream>>>(x, xp);
    kqk <<<NBLK, 512, 0, stream>>>(xp, y, S, pmax);
    ksp <<<256, 512, 0, stream>>>(x, y, S, pmax, sig, out);
}